// Round 6
// baseline (236.336 us; speedup 1.0000x reference)
//
#include <hip/hip_runtime.h>
#include <cstdint>
#include <cstddef>

#define T_SEQ 2048
#define DMODEL 2048
#define HQ 16
#define HKV 4
#define HD 128

typedef __attribute__((ext_vector_type(4))) float f32x4;
typedef __attribute__((ext_vector_type(8))) short bf16x8;
typedef __attribute__((ext_vector_type(4))) short short4v;
typedef __attribute__((ext_vector_type(2))) short short2v;
typedef __attribute__((ext_vector_type(4))) unsigned uint4v;

__device__ __forceinline__ short f2bf(float f) {
  unsigned u = __builtin_bit_cast(unsigned, f);
  u = (u + 0x7FFFu + ((u >> 16) & 1u)) >> 16;
  return (short)u;
}
__device__ __forceinline__ float bf2f(short s) {
  unsigned u = ((unsigned)(unsigned short)s) << 16;
  return __builtin_bit_cast(float, u);
}
// pack hi16(a) | hi16(b)<<16 (bf16 truncation) in ONE v_perm_b32
__device__ __forceinline__ unsigned pk_hi16(float a, float b) {
  return __builtin_amdgcn_perm(__builtin_bit_cast(unsigned, b),
                               __builtin_bit_cast(unsigned, a), 0x07060302u);
}

__device__ __forceinline__ void g2lds16(const void* g, void* l) {
  __builtin_amdgcn_global_load_lds(
      (const __attribute__((address_space(1))) void*)g,
      (__attribute__((address_space(3))) void*)l, 16, 0, 0);
}

// ---------------- convert f32 -> bf16 ----------------
__global__ void cvt_kernel(const float* __restrict__ src, short* __restrict__ dst, int n) {
  int idx = blockIdx.x * 256 + threadIdx.x;
  int i = idx * 4;
  if (i >= n) return;
  float4 v = *(const float4*)(src + i);
  short4v o;
  o[0] = f2bf(v.x); o[1] = f2bf(v.y); o[2] = f2bf(v.z); o[3] = f2bf(v.w);
  *(short4v*)(dst + i) = o;
}

// ---------------- transpose + convert: src [R][C] f32 -> dst [C][R] bf16 ----------------
__global__ void transpose_cvt(const float* __restrict__ src, short* __restrict__ dst, int R, int C) {
  __shared__ float tile[32][33];
  int c0 = blockIdx.x * 32, r0 = blockIdx.y * 32;
  int tx = threadIdx.x, ty = threadIdx.y;
  #pragma unroll
  for (int i = 0; i < 32; i += 8)
    tile[ty + i][tx] = src[(size_t)(r0 + ty + i) * C + c0 + tx];
  __syncthreads();
  #pragma unroll
  for (int i = 0; i < 32; i += 8)
    dst[(size_t)(c0 + ty + i) * R + r0 + tx] = f2bf(tile[tx][ty + i]);
}

// ---------------- GEMM: C = A[M][K] * B[K][N], BT is B transposed [N][K] ----------------
template <int MODE>
__global__ __launch_bounds__(256, 2) void gemm_kernel(
    const short* __restrict__ A, const short* __restrict__ BT,
    void* __restrict__ C0, void* __restrict__ C1, void* __restrict__ C2,
    int M, int N, int K)
{
  __shared__ short As[128 * 32];
  __shared__ short Bs[128 * 32];
  const int tid = threadIdx.x;
  const int lane = tid & 63, w = tid >> 6;
  const int l15 = lane & 15, g = lane >> 4;
  const int m0 = blockIdx.y * 128, n0 = blockIdx.x * 128;
  const int wm = (w >> 1) * 64, wn = (w & 1) * 64;

  f32x4 acc[4][4] = {};

  for (int k0 = 0; k0 < K; k0 += 32) {
    __syncthreads();
    #pragma unroll
    for (int call = 0; call < 2; call++) {
      int tau = call * 256 + tid;
      int row = tau >> 2, c = tau & 3;
      int swz = (row & 3) ^ ((row >> 2) & 3);
      g2lds16(A + (size_t)(m0 + row) * K + k0 + ((c ^ swz) << 3),
              (char*)As + call * 4096 + w * 1024);
      g2lds16(BT + (size_t)(n0 + row) * K + k0 + ((c ^ swz) << 3),
              (char*)Bs + call * 4096 + w * 1024);
    }
    __syncthreads();
    bf16x8 af[4], bfr[4];
    #pragma unroll
    for (int mi = 0; mi < 4; mi++) {
      int row = wm + mi * 16 + l15;
      int ch = g ^ ((row & 3) ^ ((row >> 2) & 3));
      af[mi] = *(const bf16x8*)(As + row * 32 + ch * 8);
    }
    #pragma unroll
    for (int ni = 0; ni < 4; ni++) {
      int row = wn + ni * 16 + l15;
      int ch = g ^ ((row & 3) ^ ((row >> 2) & 3));
      bfr[ni] = *(const bf16x8*)(Bs + row * 32 + ch * 8);
    }
    #pragma unroll
    for (int mi = 0; mi < 4; mi++)
      #pragma unroll
      for (int ni = 0; ni < 4; ni++)
        acc[mi][ni] = __builtin_amdgcn_mfma_f32_16x16x32_bf16(af[mi], bfr[ni], acc[mi][ni], 0, 0, 0);
  }

  if (MODE == 1) {
    float* C = (float*)C0;
    #pragma unroll
    for (int mi = 0; mi < 4; mi++)
      #pragma unroll
      for (int r = 0; r < 4; r++) {
        int m = m0 + wm + mi * 16 + g * 4 + r;
        #pragma unroll
        for (int ni = 0; ni < 4; ni++)
          C[(size_t)m * N + n0 + wn + ni * 16 + l15] = acc[mi][ni][r];
      }
  } else {
    short* Cb; int ldc, nc;
    if (MODE == 0) { Cb = (short*)C0; ldc = N; nc = n0; }
    else {
      if (n0 < 2048)      { Cb = (short*)C0; ldc = 2048; nc = n0; }
      else if (n0 < 2560) { Cb = (short*)C1; ldc = 512;  nc = n0 - 2048; }
      else                { Cb = (short*)C2; ldc = 512;  nc = n0 - 2560; }
    }
    #pragma unroll
    for (int mi = 0; mi < 4; mi++)
      #pragma unroll
      for (int r = 0; r < 4; r++) {
        int m = m0 + wm + mi * 16 + g * 4 + r;
        #pragma unroll
        for (int ni = 0; ni < 4; ni++)
          Cb[(size_t)m * ldc + nc + wn + ni * 16 + l15] = f2bf(acc[mi][ni][r]);
      }
  }
}

// ---------------- RoPE in-place on [B*T][NH][128] bf16 ----------------
__global__ void rope_kernel(short* __restrict__ buf, int NH, float scale, int npairs) {
  int idx = blockIdx.x * 256 + threadIdx.x;
  if (idx >= npairs) return;
  int i = idx & 63;
  int th = idx >> 6;
  int t = (th / NH) % T_SEQ;
  size_t base = (size_t)th * 128;
  float invf = exp2f(-(float)i * 0.20762050593046014f);
  float theta = (float)t * invf;
  float sn, cs;
  sincosf(theta, &sn, &cs);
  float a = bf2f(buf[base + i]);
  float b = bf2f(buf[base + 64 + i]);
  buf[base + i]      = f2bf((a * cs - b * sn) * scale);
  buf[base + 64 + i] = f2bf((b * cs + a * sn) * scale);
}

// ---------------- Flash attention (causal, GQA), swapped-operand MFMA ----------------
// 512 threads = 8 waves, 16 q-rows/wave, kv tile 64. K AND V^T double-buffered ->
// ONE __syncthreads per tile (its implicit vmcnt/lgkmcnt drain is the fence for
// both the K DMA and the V ds_writes). loadV issued before stageK so writeV only
// needs vmcnt(2), not a full drain.
__global__ __launch_bounds__(512, 4) void attn_kernel(
    const short* __restrict__ qg, const short* __restrict__ kg,
    const short* __restrict__ vg, short* __restrict__ og)
{
  __shared__ short Ks[2][64 * 128];  // 32 KB
  __shared__ short Vt[2][128 * 64];  // 32 KB
  const int tid = threadIdx.x;
  const int lane = tid & 63, w = tid >> 6;          // 8 waves
  const int l15 = lane & 15, g = lane >> 4;
  const int b = blockIdx.z;
  const int qti = b ? (15 - (int)blockIdx.x) : (int)blockIdx.x;  // causal pairing balance
  const int qt0 = qti * 128;
  const int h = blockIdx.y, hk = h >> 2;
  const int qw0 = qt0 + w * 16;                     // 16 q-rows per wave

  // Q fragments: lane holds Q[q=qw0+l15][d=(ks*4+g)*8 ..+7]
  bf16x8 qf[4];
  {
    size_t t = (size_t)b * T_SEQ + qw0 + l15;
    const short* qp = qg + (t * HQ + h) * HD;
    #pragma unroll
    for (int ks = 0; ks < 4; ks++)
      qf[ks] = *(const bf16x8*)(qp + ks * 32 + g * 8);
  }

  f32x4 of[8] = {};                  // O^T acc [dc]: d=dc*16+4g+r, q=l15
  float m2 = -INFINITY;
  float ls = 0.f;

  const short* kbase = kg + ((size_t)b * T_SEQ * HKV + hk) * HD;
  const short* vbase = vg + ((size_t)b * T_SEQ * HKV + hk) * HD;

  // V staging assignment (512 threads): 2 kv rows x 8 d each
  const int kv2 = (tid & 31) * 2;
  const int d8s = (tid >> 5) * 8;
  // stored position of kv (P k-order): p = (kv>>5)*32 + ((kv&15)>>2)*8 + ((kv>>4)&1)*4 + (kv&3)
  const int p0 = (kv2 >> 5) * 32 + ((kv2 & 15) >> 2) * 8 + ((kv2 >> 4) & 1) * 4 + (kv2 & 3);
  const int nt = (qt0 + 128) >> 6;

  bf16x8 vr[2];

  auto stageK = [&](int t, int nb) {
    #pragma unroll
    for (int call = 0; call < 2; call++) {
      int tau = call * 512 + tid;
      int kv = tau >> 4, c = tau & 15;
      g2lds16(kbase + (size_t)(t * 64 + kv) * (HKV * HD) + ((c ^ (kv & 7)) << 3),
              (char*)Ks[nb] + call * 8192 + w * 1024);
    }
  };
  auto loadV = [&](int t) {
    const short* vp = vbase + (size_t)(t * 64 + kv2) * (HKV * HD) + d8s;
    vr[0] = *(const bf16x8*)(vp);
    vr[1] = *(const bf16x8*)(vp + HKV * HD);
  };
  auto writeV = [&](int nb) {
    #pragma unroll
    for (int e = 0; e < 8; e++) {
      int row = d8s + e;
      int addr = row * 64 + (((p0 >> 3) ^ e) << 3) + (p0 & 7);
      short2v t2; t2[0] = vr[0][e]; t2[1] = vr[1][e];
      *(short2v*)(&Vt[nb][addr]) = t2;
    }
  };

  // prologue: tile 0 into buffer 0
  stageK(0, 0);
  loadV(0);
  __syncthreads();                    // K(0) staged; vr valid (compiler vmcnt)
  writeV(0);
  __syncthreads();                    // Vt[0] visible

  for (int t = 0; t < nt; t++) {
    const int kv0 = t * 64;
    const int cur = t & 1, nb = cur ^ 1;
    const bool haveNext = (t + 1 < nt);
    if (haveNext) { loadV(t + 1); stageK(t + 1, nb); }

    if (kv0 <= qw0 + 15) {
      const short* Kc = Ks[cur];
      const short* Vc = Vt[cur];
      f32x4 sacc[4] = {};
      __builtin_amdgcn_s_setprio(1);
      #pragma unroll
      for (int ks = 0; ks < 4; ks++) {
        bf16x8 kf[4];
        #pragma unroll
        for (int kt = 0; kt < 4; kt++) {
          int row = kt * 16 + l15;
          int ch = (ks * 4 + g) ^ (row & 7);
          kf[kt] = *(const bf16x8*)(Kc + row * 128 + ch * 8);
        }
        #pragma unroll
        for (int kt = 0; kt < 4; kt++)
          sacc[kt] = __builtin_amdgcn_mfma_f32_16x16x32_bf16(kf[kt], qf[ks], sacc[kt], 0, 0, 0);
      }
      __builtin_amdgcn_s_setprio(0);
      const bool needmask = (kv0 + 63) > qw0;
      const int qpos = qw0 + l15;
      float vmax = -INFINITY;
      #pragma unroll
      for (int kt = 0; kt < 4; kt++)
        #pragma unroll
        for (int r = 0; r < 4; r++) {
          int kvpos = kv0 + kt * 16 + g * 4 + r;
          float sv = sacc[kt][r];
          if (needmask && kvpos > qpos) sv = -INFINITY;
          sacc[kt][r] = sv;
          vmax = fmaxf(vmax, sv);
        }
      vmax = fmaxf(vmax, __shfl_xor(vmax, 16));
      vmax = fmaxf(vmax, __shfl_xor(vmax, 32));
      if (!__all(vmax <= m2 + 8.0f)) {   // defer-max (T13)
        float mnew = fmaxf(m2, vmax);
        float resc = exp2f(m2 - mnew);
        m2 = mnew;
        ls *= resc;
        #pragma unroll
        for (int dc = 0; dc < 8; dc++) of[dc] *= resc;
      }
      float lsum = 0.f;
      #pragma unroll
      for (int kt = 0; kt < 4; kt++)
        #pragma unroll
        for (int r = 0; r < 4; r++) {
          float p = exp2f(sacc[kt][r] - m2);
          sacc[kt][r] = p;
          lsum += p;
        }
      lsum += __shfl_xor(lsum, 16);
      lsum += __shfl_xor(lsum, 32);
      ls += lsum;
      // pack P into stored k-order: frag ktw: j<4 -> sacc[2ktw], j>=4 -> sacc[2ktw+1]
      bf16x8 pb[2];
      #pragma unroll
      for (int ktw = 0; ktw < 2; ktw++) {
        uint4v pw;
        pw[0] = pk_hi16(sacc[2 * ktw][0], sacc[2 * ktw][1]);
        pw[1] = pk_hi16(sacc[2 * ktw][2], sacc[2 * ktw][3]);
        pw[2] = pk_hi16(sacc[2 * ktw + 1][0], sacc[2 * ktw + 1][1]);
        pw[3] = pk_hi16(sacc[2 * ktw + 1][2], sacc[2 * ktw + 1][3]);
        pb[ktw] = __builtin_bit_cast(bf16x8, pw);
      }
      // O^T += V^T * P : one swizzled ds_read_b128 per fragment
      __builtin_amdgcn_s_setprio(1);
      #pragma unroll
      for (int ktw = 0; ktw < 2; ktw++)
        #pragma unroll
        for (int dc = 0; dc < 8; dc++) {
          int row = dc * 16 + l15;
          bf16x8 vf = *(const bf16x8*)(&Vc[row * 64 + ((ktw * 32 + g * 8) ^ ((l15 & 7) << 3))]);
          of[dc] = __builtin_amdgcn_mfma_f32_16x16x32_bf16(vf, pb[ktw], of[dc], 0, 0, 0);
        }
      __builtin_amdgcn_s_setprio(0);
    }

    if (haveNext) writeV(nb);        // other buffer; overlaps other waves' compute
    __syncthreads();                 // single fence: drains K-DMA + V ds_writes,
                                     // and closes reads of buffer `cur`
  }

  // epilogue: normalize and store O (lane: q=l15, d=dc*16+4g+r)
  {
    float inv = 1.0f / ls;
    size_t t = (size_t)b * T_SEQ + qw0 + l15;
    short* op = og + (t * HQ + h) * HD;
    #pragma unroll
    for (int dc = 0; dc < 8; dc++) {
      short4v o;
      #pragma unroll
      for (int r = 0; r < 4; r++) o[r] = f2bf(of[dc][r] * inv);
      *(short4v*)(op + dc * 16 + g * 4) = o;
    }
  }
}

extern "C" void kernel_launch(void* const* d_in, const int* in_sizes, int n_in,
                              void* d_out, int out_size, void* d_ws, size_t ws_size,
                              hipStream_t stream) {
  (void)in_sizes; (void)n_in; (void)out_size; (void)ws_size;
  const float* x  = (const float*)d_in[0];
  const float* Wq = (const float*)d_in[2];
  const float* Wk = (const float*)d_in[3];
  const float* Wv = (const float*)d_in[4];
  const float* Wo = (const float*)d_in[5];

  char* ws = (char*)d_ws;
  short* xb   = (short*)(ws);                    // 16 MB   [4096][2048]
  short* wall = (short*)(ws + 16777216);         // 12.6 MB [3072][2048] = WqT|WkT|WvT
  short* wkT  = wall + (size_t)2048 * 2048;
  short* wvT  = wall + (size_t)2560 * 2048;
  short* woT  = (short*)(ws + 29360128);         // 8 MB    [2048][2048]
  short* qb   = (short*)(ws + 37748736);         // 16 MB   [B,T,HQ,128]
  short* kb   = (short*)(ws + 54525952);         // 4 MB    [B,T,HKV,128]
  short* vb   = (short*)(ws + 58720256);         // 4 MB    [B,T,HKV,128]
  short* ab   = (short*)(ws + 62914560);         // 16 MB   [4096][2048]

  const float MULT = 0.08838834764831845f;
  const float LOG2E = 1.4426950408889634f;
  const float QSCALE = MULT * LOG2E;

  dim3 tb(32, 8);
  cvt_kernel<<<8192, 256, 0, stream>>>(x, xb, 8388608);
  transpose_cvt<<<dim3(64, 64), tb, 0, stream>>>(Wq, wall, 2048, 2048);
  transpose_cvt<<<dim3(16, 64), tb, 0, stream>>>(Wk, wkT, 2048, 512);
  transpose_cvt<<<dim3(16, 64), tb, 0, stream>>>(Wv, wvT, 2048, 512);
  transpose_cvt<<<dim3(64, 64), tb, 0, stream>>>(Wo, woT, 2048, 2048);

  // fused QKV projection: [4096][2048] x [2048][3072] -> qb|kb|vb
  gemm_kernel<2><<<dim3(24, 32), 256, 0, stream>>>(xb, wall, qb, kb, vb, 4096, 3072, 2048);

  rope_kernel<<<16384, 256, 0, stream>>>(qb, HQ, QSCALE, 4194304);
  rope_kernel<<<4096, 256, 0, stream>>>(kb, HKV, 1.0f, 1048576);

  attn_kernel<<<dim3(16, 16, 2), 512, 0, stream>>>(qb, kb, vb, ab);

  gemm_kernel<1><<<dim3(16, 32), 256, 0, stream>>>(ab, woT, d_out, nullptr, nullptr, 4096, 2048, 2048);
}